// Round 10
// baseline (259.704 us; speedup 1.0000x reference)
//
#include <hip/hip_runtime.h>

#define V 2197000        // 130^3
#define NV4 549250       // V/4
#define VPL 16900        // 130*130
#define TZ 10
#define DQY 17
#define DQZ 14
#define NROWS 238        // DQZ*DQY
#define A4P 16           // row stride (dwords); quad q of row y at slot (q+y)&3
#define A4SZ (NROWS*A4P) // 3808 dwords
#define NXY 90
#define NZB 13
#define NWG 2340

// ---- direct-global row loader: reproduces xp (zero ring + edge replicate) in regs ----
__device__ __forceinline__ void load_row(const float* __restrict__ g, int ax0, int klass,
                                         bool zero, float (&r)[24]){
  if (zero){
    #pragma unroll
    for (int j=0;j<24;++j) r[j]=0.f;
    return;
  }
  const float4* p = (const float4*)(g + ax0);
  if (klass==1){          // bxg 1..6: fully interior, r[j] = g[ax0+3+j]
    float vv[28];
    #pragma unroll
    for (int j=0;j<7;++j){ float4 v=p[j]; vv[4*j]=v.x; vv[4*j+1]=v.y; vv[4*j+2]=v.z; vv[4*j+3]=v.w; }
    #pragma unroll
    for (int j=0;j<24;++j) r[j]=vv[j+3];
  } else if (klass==0){   // bxg 0: qx=j; j=0 zero ring, j=1..3 replicate x=0
    float vv[24];
    #pragma unroll
    for (int j=0;j<6;++j){ float4 v=p[j]; vv[4*j]=v.x; vv[4*j+1]=v.y; vv[4*j+2]=v.z; vv[4*j+3]=v.w; }
    r[0]=0.f; r[1]=vv[0]; r[2]=vv[0]; r[3]=vv[0];
    #pragma unroll
    for (int j=4;j<24;++j) r[j]=vv[j-3];
  } else if (klass==2){   // bxg 7: qx=110+j; j=21,22 replicate x=127; j=23 zero ring
    float vv[24];
    #pragma unroll
    for (int j=0;j<6;++j){ float4 v=p[j]; vv[4*j]=v.x; vv[4*j+1]=v.y; vv[4*j+2]=v.z; vv[4*j+3]=v.w; }
    #pragma unroll
    for (int j=0;j<21;++j) r[j]=vv[j+3];
    r[21]=vv[23]; r[22]=vv[23]; r[23]=0.f;
  } else {                // bxg 8: qx=126+j; j<=4 real, 5,6 replicate, 7 zero, rest unused
    float4 v0=p[0], v1=p[1];
    r[0]=v0.w; r[1]=v1.x; r[2]=v1.y; r[3]=v1.z; r[4]=v1.w;
    r[5]=v1.w; r[6]=v1.w;
    #pragma unroll
    for (int j=7;j<24;++j) r[j]=0.f;
  }
}

// ---- A stage: fused diff^2 + 5-tap x-filter, pure VALU; slot-rotated b128 writes ----
template<int S1X, int S2X>
__device__ __forceinline__ void aphase(const float (&r1)[24], const float (&r2)[24],
                                       float* __restrict__ buf, const int (&wb)[4],
                                       int bxg, bool arow){
  if (!arow) return;
  float dd[20];
  #pragma unroll
  for (int t=0;t<20;++t){ float d = r1[t+S1X]-r2[t+S2X]; dd[t]=d*d; }
  float W[16];
  W[0]=dd[0]+dd[1]+dd[2]+dd[3]+dd[4];
  #pragma unroll
  for (int j=1;j<16;++j) W[j]=W[j-1]+dd[j+4]-dd[j-1];
  float Ao[16];
  if (bxg==0){
    Ao[0]=W[0]+2.f*dd[0]-dd[3]-dd[4];
    Ao[1]=W[0]+dd[0]-dd[4];
    #pragma unroll
    for(int j=2;j<16;++j) Ao[j]=W[j-2];
  } else if (bxg==8){
    Ao[0]=W[0]+dd[3]-dd[4];
    Ao[1]=W[0]-dd[0]+2.f*dd[3]-dd[4];
    #pragma unroll
    for(int j=2;j<16;++j) Ao[j]=W[j-2];
  } else {
    #pragma unroll
    for(int j=0;j<16;++j) Ao[j]=W[j];
  }
  #pragma unroll
  for (int q=0;q<4;++q)
    *(float4*)(buf + wb[q]) = make_float4(Ao[4*q],Ao[4*q+1],Ao[4*q+2],Ao[4*q+3]);
}

// ---- merged Y+Z stage, zh-split b64: thread owns (zh,oy,x-pair); 45 ds_read_b64
// (9 z-planes x 5 y-taps), sliding-z over 5 outputs, b64 global stores.
// Bank math: per instr 128 dwords over 32 banks, exactly 4/bank = b64 floor. ----
__device__ __forceinline__ void yzphase(const float2* __restrict__ a2, const int (&fb)[5],
                                        bool yzact, bool valid, float* __restrict__ gp,
                                        float2 (&rmin)[5], float2 (&rsum)[5],
                                        bool first, int cV){
  if (!yzact) return;
  float2 By[9];
  #pragma unroll
  for (int j=0;j<9;++j){
    float2 a0 = a2[fb[0] + j*136];
    float2 a1 = a2[fb[1] + j*136];
    float2 av = a2[fb[2] + j*136];
    float2 a3 = a2[fb[3] + j*136];
    float2 a4 = a2[fb[4] + j*136];
    By[j].x = a0.x+a1.x+av.x+a3.x+a4.x;
    By[j].y = a0.y+a1.y+av.y+a3.y+a4.y;
  }
  float2 S;
  S.x = By[0].x+By[1].x+By[2].x+By[3].x+By[4].x;
  S.y = By[0].y+By[1].y+By[2].y+By[3].y+By[4].y;
  #pragma unroll
  for (int k=0;k<5;++k){
    if (valid) *(float2*)(gp + cV + k*VPL) = S;
    if (first){ rmin[k]=S; rsum[k]=S; }
    else {
      rmin[k].x = fminf(rmin[k].x,S.x); rmin[k].y = fminf(rmin[k].y,S.y);
      rsum[k].x += S.x;                 rsum[k].y += S.y;
    }
    if (k<4){ S.x += By[k+5].x-By[k].x; S.y += By[k+5].y-By[k].y; }
  }
}

#define PIN24(r) asm volatile("" : \
  "+v"(r[0]),"+v"(r[1]),"+v"(r[2]),"+v"(r[3]),"+v"(r[4]),"+v"(r[5]), \
  "+v"(r[6]),"+v"(r[7]),"+v"(r[8]),"+v"(r[9]),"+v"(r[10]),"+v"(r[11]), \
  "+v"(r[12]),"+v"(r[13]),"+v"(r[14]),"+v"(r[15]),"+v"(r[16]),"+v"(r[17]), \
  "+v"(r[18]),"+v"(r[19]),"+v"(r[20]),"+v"(r[21]),"+v"(r[22]),"+v"(r[23]))

__global__ __launch_bounds__(256,3) void mind_main(const float* __restrict__ x,
                                                   float* __restrict__ pre,
                                                   float* __restrict__ bsum){
  __shared__ float A4[2*A4SZ];
  __shared__ float wred[4];

  const int tid = threadIdx.x;
  // bijective XCD-chunk swizzle (nwg=2340: q=292, r=4)
  const int orig = blockIdx.x;
  const int xcd = orig & 7, posi = orig >> 3;
  const int t = (xcd < 4) ? xcd*293 + posi : 1172 + (xcd-4)*292 + posi;
  const int xyb = t % NXY;
  const int rest = t / NXY;
  const int zb = rest % NZB;
  const int b  = rest / NZB;
  const int bxg = xyb % 9, byg = xyb / 9;
  const int p0x = bxg*16, p0y = byg*13, p0z = zb*TZ;

  const float* xb = x + b*2097152;
  const int ax0   = (bxg==0) ? 0 : 16*bxg-8;
  const int klass = (bxg==0) ? 0 : (bxg<=6) ? 1 : (bxg==7) ? 2 : 3;

  // ---- per-thread A-row geometry: row index == tid = tz*17+ty (y fastest) ----
  const bool arow = tid < NROWS;
  const int tz = tid/DQY, ty = tid - tz*DQY;
  const int ez = min(max(p0z-2+tz,0),129);
  const int ey = min(max(p0y-2+ty,0),129);
  const int izA = min(max(ez-1,0),127);
  const int izC = min(ez+1,127);
  const int izE = max(ez-3,0);
  const int iyA = min(max(ey-1,0),127);
  const int iyB = max(ey-3,0);
  const int iyD = min(ey+1,127);
  const bool zB = (ey==0), zD = (ey==129), zE = (ez==0), zC = (ez==129);
  const float* gA = xb + (izA*128+iyA)*128;
  const float* gB = xb + (izA*128+iyB)*128;
  const float* gC = xb + (izC*128+iyA)*128;
  const float* gD = xb + (izA*128+iyD)*128;
  const float* gE = xb + (izE*128+iyA)*128;

  // A write bases: row=tid, quad q at slot (q+ty)&3
  int wb[4];
  #pragma unroll
  for (int q=0;q<4;++q) wb[q] = tid*A4P + ((q+ty)&3)*4;

  // ---- yz mapping: (oy 0..12) x (xh 0..7 x-pairs) x (zh 0..1 z-halves) ----
  const int oy = tid>>4, xh = (tid>>1)&7, zh = tid&1;
  const int xq = xh>>1, jo = xh&1;
  const bool yzact = tid < 208;
  const bool valid = yzact && ((bxg<8) || (xh==0));
  int fb[5];
  #pragma unroll
  for (int y5=0;y5<5;++y5){
    const int row0 = 85*zh + oy + y5;     // z enters via +j*136 (imm, float2 units)
    fb[y5] = row0*8 + ((xq + oy + y5)&3)*2 + jo;
  }
  float* gp = pre + ((long)b*12*V + (p0z + 5*zh)*VPL + (p0y+oy)*130 + (p0x + 2*xh));
  float2 rmin[5], rsum[5];

  const float2* const a20 = (const float2*)A4;
  const float2* const a21 = (const float2*)(A4 + A4SZ);
  float* const b0 = A4;
  float* const b1 = A4 + A4SZ;

  // ---- load 4 rows (B,E,A,D) up front; C later (max 4-5 rows live) ----
  float rA[24],rB[24],rC[24],rD[24],rE[24];
  if (arow){
    load_row(gB,ax0,klass,zB,rB);
    load_row(gE,ax0,klass,zE,rE);
    load_row(gA,ax0,klass,false,rA);
    load_row(gD,ax0,klass,zD,rD);
    PIN24(rB); PIN24(rE); PIN24(rA); PIN24(rD);
  }

  // ---- 12 channels, double-buffered A4, 1 barrier/channel; yz lags aphase by 1 ----
  aphase<2,2>(rB,rE,b0,wb,bxg,arow);                    // c1
  __syncthreads();
  aphase<0,2>(rA,rE,b1,wb,bxg,arow);                    // c0
  yzphase(a20,fb,yzact,valid,gp,rmin,rsum,true , 1*V);
  __syncthreads();
  aphase<4,2>(rA,rE,b0,wb,bxg,arow);                    // c3
  yzphase(a21,fb,yzact,valid,gp,rmin,rsum,false, 0*V);
  __syncthreads();
  aphase<2,2>(rD,rE,b1,wb,bxg,arow);                    // c8 (last E use)
  if (arow){ load_row(gC,ax0,klass,zC,rC); PIN24(rC); }
  yzphase(a20,fb,yzact,valid,gp,rmin,rsum,false, 3*V);
  __syncthreads();
  aphase<2,0>(rB,rA,b0,wb,bxg,arow);                    // c2
  yzphase(a21,fb,yzact,valid,gp,rmin,rsum,false, 8*V);
  __syncthreads();
  aphase<4,2>(rA,rB,b1,wb,bxg,arow);                    // c4
  yzphase(a20,fb,yzact,valid,gp,rmin,rsum,false, 2*V);
  __syncthreads();
  aphase<2,2>(rC,rB,b0,wb,bxg,arow);                    // c6 (last B use)
  yzphase(a21,fb,yzact,valid,gp,rmin,rsum,false, 4*V);
  __syncthreads();
  aphase<2,0>(rC,rA,b1,wb,bxg,arow);                    // c5
  yzphase(a20,fb,yzact,valid,gp,rmin,rsum,false, 6*V);
  __syncthreads();
  aphase<2,4>(rC,rA,b0,wb,bxg,arow);                    // c7
  yzphase(a21,fb,yzact,valid,gp,rmin,rsum,false, 5*V);
  __syncthreads();
  aphase<2,2>(rD,rC,b1,wb,bxg,arow);                    // c11 (last C use)
  yzphase(a20,fb,yzact,valid,gp,rmin,rsum,false, 7*V);
  __syncthreads();
  aphase<2,0>(rD,rA,b0,wb,bxg,arow);                    // c9
  yzphase(a21,fb,yzact,valid,gp,rmin,rsum,false,11*V);
  __syncthreads();
  aphase<2,4>(rD,rA,b1,wb,bxg,arow);                    // c10
  yzphase(a20,fb,yzact,valid,gp,rmin,rsum,false, 9*V);
  __syncthreads();
  yzphase(a21,fb,yzact,valid,gp,rmin,rsum,false,10*V);

  // ---- deterministic partial sum of mind_var (raw scale) ----
  float vl = 0.f;
  if (valid){
    #pragma unroll
    for (int k=0;k<5;++k)
      vl += (rsum[k].x*(1.0f/12.0f) - rmin[k].x)
          + (rsum[k].y*(1.0f/12.0f) - rmin[k].y);
  }
  #pragma unroll
  for (int off=32; off>0; off>>=1) vl += __shfl_down(vl, off, 64);
  if ((tid&63)==0) wred[tid>>6] = vl;
  __syncthreads();
  if (tid==0) bsum[orig] = wred[0]+wred[1]+wred[2]+wred[3];
}

// ---------------- deterministic reduce for m ----------------
__global__ __launch_bounds__(256) void reduce_bsum(const float* __restrict__ bsum, float* wsf){
  __shared__ float sm[256];
  float s = 0.f;
  for (int i = threadIdx.x; i < NWG; i += 256) s += bsum[i];
  sm[threadIdx.x] = s;
  __syncthreads();
  for (int w = 128; w > 0; w >>= 1){
    if (threadIdx.x < w) sm[threadIdx.x] += sm[threadIdx.x + w];
    __syncthreads();
  }
  if (threadIdx.x == 0) wsf[2] = sm[0] * (1.0f/4394000.0f);
}

// ---------------- finalize: min/mean/clamp/exp in-place on raw ssd ----------------
__global__ __launch_bounds__(256) void final_kernel(float* __restrict__ out,
                                                    const float* __restrict__ wsf){
  const int q = blockIdx.x*256 + threadIdx.x;
  if (q >= 2*NV4) return;
  const float m = wsf[2];
  const float lo = m*0.001f, hi = m*1000.f;
  const int b = q / NV4;
  const int vq = q - b*NV4;
  float4* o4 = (float4*)out;
  const int ob = b*12*NV4 + vq;
  float4 p[12];
  #pragma unroll
  for (int c=0;c<12;++c) p[c] = o4[ob + c*NV4];
  float4 mn = p[0], sm = p[0];
  #pragma unroll
  for (int c=1;c<12;++c){
    mn.x = fminf(mn.x,p[c].x); mn.y = fminf(mn.y,p[c].y);
    mn.z = fminf(mn.z,p[c].z); mn.w = fminf(mn.w,p[c].w);
    sm.x += p[c].x; sm.y += p[c].y; sm.z += p[c].z; sm.w += p[c].w;
  }
  const float rx = 1.f/fminf(fmaxf(sm.x*(1.f/12.f)-mn.x, lo), hi);
  const float ry = 1.f/fminf(fmaxf(sm.y*(1.f/12.f)-mn.y, lo), hi);
  const float rz = 1.f/fminf(fmaxf(sm.z*(1.f/12.f)-mn.z, lo), hi);
  const float rw = 1.f/fminf(fmaxf(sm.w*(1.f/12.f)-mn.w, lo), hi);
  #pragma unroll
  for (int c=0;c<12;++c){
    float4 e;
    e.x = __expf(-(p[c].x-mn.x)*rx);
    e.y = __expf(-(p[c].y-mn.y)*ry);
    e.z = __expf(-(p[c].z-mn.z)*rz);
    e.w = __expf(-(p[c].w-mn.w)*rw);
    o4[ob + c*NV4] = e;
  }
}

extern "C" void kernel_launch(void* const* d_in, const int* in_sizes, int n_in,
                              void* d_out, int out_size, void* d_ws, size_t ws_size,
                              hipStream_t stream){
  (void)in_sizes; (void)n_in; (void)out_size; (void)ws_size;
  const float* x = (const float*)d_in[0];
  float* out = (float*)d_out;
  float* wsf = (float*)d_ws;
  float* bsum = (float*)((char*)d_ws + 64);

  hipLaunchKernelGGL(mind_main, dim3(NWG), dim3(256), 0, stream, x, out, bsum);
  hipLaunchKernelGGL(reduce_bsum, dim3(1), dim3(256), 0, stream, bsum, wsf);
  hipLaunchKernelGGL(final_kernel, dim3((2*NV4+255)/256), dim3(256), 0, stream, out, wsf);
}

// Round 11
// 163.114 us; speedup vs baseline: 1.5922x; 1.5922x over previous
//
#include <hip/hip_runtime.h>

#define V 2197000        // 130^3
#define NV4 549250       // V/4
#define VPL 16900        // 130*130
#define TZ 10
#define DQY 17
#define DQZ 14
#define NROWS 238        // DQZ*DQY
#define A4P 16           // row stride (dwords); quad q of row y at slot (q+y)&3
#define A4SZ (NROWS*A4P) // 3808 dwords
#define NXY 90
#define NZB 13
#define NWG 2340

// ---- direct-global row loader: reproduces xp (zero ring + edge replicate) in regs ----
__device__ __forceinline__ void load_row(const float* __restrict__ g, int ax0, int klass,
                                         bool zero, float (&r)[24]){
  if (zero){
    #pragma unroll
    for (int j=0;j<24;++j) r[j]=0.f;
    return;
  }
  const float4* p = (const float4*)(g + ax0);
  if (klass==1){          // bxg 1..6: fully interior, r[j] = g[ax0+3+j]
    float vv[28];
    #pragma unroll
    for (int j=0;j<7;++j){ float4 v=p[j]; vv[4*j]=v.x; vv[4*j+1]=v.y; vv[4*j+2]=v.z; vv[4*j+3]=v.w; }
    #pragma unroll
    for (int j=0;j<24;++j) r[j]=vv[j+3];
  } else if (klass==0){   // bxg 0: qx=j; j=0 zero ring, j=1..3 replicate x=0
    float vv[24];
    #pragma unroll
    for (int j=0;j<6;++j){ float4 v=p[j]; vv[4*j]=v.x; vv[4*j+1]=v.y; vv[4*j+2]=v.z; vv[4*j+3]=v.w; }
    r[0]=0.f; r[1]=vv[0]; r[2]=vv[0]; r[3]=vv[0];
    #pragma unroll
    for (int j=4;j<24;++j) r[j]=vv[j-3];
  } else if (klass==2){   // bxg 7: qx=110+j; j=21,22 replicate x=127; j=23 zero ring
    float vv[24];
    #pragma unroll
    for (int j=0;j<6;++j){ float4 v=p[j]; vv[4*j]=v.x; vv[4*j+1]=v.y; vv[4*j+2]=v.z; vv[4*j+3]=v.w; }
    #pragma unroll
    for (int j=0;j<21;++j) r[j]=vv[j+3];
    r[21]=vv[23]; r[22]=vv[23]; r[23]=0.f;
  } else {                // bxg 8: qx=126+j; j<=4 real, 5,6 replicate, 7 zero, rest unused
    float4 v0=p[0], v1=p[1];
    r[0]=v0.w; r[1]=v1.x; r[2]=v1.y; r[3]=v1.z; r[4]=v1.w;
    r[5]=v1.w; r[6]=v1.w;
    #pragma unroll
    for (int j=7;j<24;++j) r[j]=0.f;
  }
}

// ---- A stage: fused diff^2 + 5-tap x-filter, pure VALU; slot-rotated b128 writes ----
template<int S1X, int S2X>
__device__ __forceinline__ void aphase(const float (&r1)[24], const float (&r2)[24],
                                       float* __restrict__ buf, const int (&wb)[4],
                                       int bxg, bool arow){
  if (!arow) return;
  float dd[20];
  #pragma unroll
  for (int t=0;t<20;++t){ float d = r1[t+S1X]-r2[t+S2X]; dd[t]=d*d; }
  float W[16];
  W[0]=dd[0]+dd[1]+dd[2]+dd[3]+dd[4];
  #pragma unroll
  for (int j=1;j<16;++j) W[j]=W[j-1]+dd[j+4]-dd[j-1];
  float Ao[16];
  if (bxg==0){
    Ao[0]=W[0]+2.f*dd[0]-dd[3]-dd[4];
    Ao[1]=W[0]+dd[0]-dd[4];
    #pragma unroll
    for(int j=2;j<16;++j) Ao[j]=W[j-2];
  } else if (bxg==8){
    Ao[0]=W[0]+dd[3]-dd[4];
    Ao[1]=W[0]-dd[0]+2.f*dd[3]-dd[4];
    #pragma unroll
    for(int j=2;j<16;++j) Ao[j]=W[j-2];
  } else {
    #pragma unroll
    for(int j=0;j<16;++j) Ao[j]=W[j];
  }
  #pragma unroll
  for (int q=0;q<4;++q)
    *(float4*)(buf + wb[q]) = make_float4(Ao[4*q],Ao[4*q+1],Ao[4*q+2],Ao[4*q+3]);
}

// ---- merged Y+Z stage: 5-tap y via 5 precomputed rotated bases; z offsets are
// compile-time immediates (z*272 dwords). Proven 2-lanes/bank (free) per read.
// Stores: one z-plane at a time per thread (L2 write-merge-clean pattern). ----
__device__ __forceinline__ void yzphase(const float* __restrict__ buf, const int (&fb)[5],
                                        bool yzact, bool valid, float* __restrict__ gp,
                                        float (&rmin)[10], float (&rsum)[10],
                                        bool first, int cV){
  if (!yzact) return;
  float By[14];
  #pragma unroll
  for (int z=0;z<14;++z){
    By[z] = buf[fb[0]+z*272] + buf[fb[1]+z*272] + buf[fb[2]+z*272]
          + buf[fb[3]+z*272] + buf[fb[4]+z*272];
  }
  float S = By[0]+By[1]+By[2]+By[3]+By[4];
  #pragma unroll
  for (int k=0;k<10;++k){
    if (valid) gp[cV + k*VPL] = S;
    if (first){ rmin[k]=S; rsum[k]=S; }
    else      { rmin[k]=fminf(rmin[k],S); rsum[k]+=S; }
    if (k<9) S += By[k+5]-By[k];
  }
}

#define PIN24(r) asm volatile("" : \
  "+v"(r[0]),"+v"(r[1]),"+v"(r[2]),"+v"(r[3]),"+v"(r[4]),"+v"(r[5]), \
  "+v"(r[6]),"+v"(r[7]),"+v"(r[8]),"+v"(r[9]),"+v"(r[10]),"+v"(r[11]), \
  "+v"(r[12]),"+v"(r[13]),"+v"(r[14]),"+v"(r[15]),"+v"(r[16]),"+v"(r[17]), \
  "+v"(r[18]),"+v"(r[19]),"+v"(r[20]),"+v"(r[21]),"+v"(r[22]),"+v"(r[23]))

__global__ __launch_bounds__(256,3) void mind_main(const float* __restrict__ x,
                                                   float* __restrict__ pre,
                                                   float* __restrict__ bsum){
  __shared__ float A4[2*A4SZ];
  __shared__ float wred[4];

  const int tid = threadIdx.x;
  // bijective XCD-chunk swizzle (nwg=2340: q=292, r=4)
  const int orig = blockIdx.x;
  const int xcd = orig & 7, posi = orig >> 3;
  const int t = (xcd < 4) ? xcd*293 + posi : 1172 + (xcd-4)*292 + posi;
  const int xyb = t % NXY;
  const int rest = t / NXY;
  const int zb = rest % NZB;
  const int b  = rest / NZB;
  const int bxg = xyb % 9, byg = xyb / 9;
  const int p0x = bxg*16, p0y = byg*13, p0z = zb*TZ;

  const float* xb = x + b*2097152;
  const int ax0   = (bxg==0) ? 0 : 16*bxg-8;
  const int klass = (bxg==0) ? 0 : (bxg<=6) ? 1 : (bxg==7) ? 2 : 3;

  // ---- per-thread A-row geometry: row index == tid = tz*17+ty (y fastest) ----
  const bool arow = tid < NROWS;
  const int tz = tid/DQY, ty = tid - tz*DQY;
  const int ez = min(max(p0z-2+tz,0),129);
  const int ey = min(max(p0y-2+ty,0),129);
  const int izA = min(max(ez-1,0),127);
  const int izC = min(ez+1,127);
  const int izE = max(ez-3,0);
  const int iyA = min(max(ey-1,0),127);
  const int iyB = max(ey-3,0);
  const int iyD = min(ey+1,127);
  const bool zB = (ey==0), zD = (ey==129), zE = (ez==0), zC = (ez==129);
  const float* gA = xb + (izA*128+iyA)*128;
  const float* gB = xb + (izA*128+iyB)*128;
  const float* gC = xb + (izC*128+iyA)*128;
  const float* gD = xb + (izA*128+iyD)*128;
  const float* gE = xb + (izE*128+iyA)*128;

  // A write bases: row=tid, quad q at slot (q+ty)&3
  int wb[4];
  #pragma unroll
  for (int q=0;q<4;++q) wb[q] = tid*A4P + ((q+ty)&3)*4;

  // yz read bases: fb[y5] = (oyT+y5)*16 + rot*4 + (oxT&3); addr = fb + z*272
  const int oyT = tid>>4, oxT = tid&15;
  const bool yzact = tid < 208;
  const bool valid = yzact && (p0x + oxT < 130);
  int fb[5];
  {
    const int ox2 = oxT>>2, oxe = oxT&3;
    #pragma unroll
    for (int y5=0;y5<5;++y5){
      const int yy = oyT + y5;
      fb[y5] = yy*16 + (((ox2 + yy)&3)<<2) + oxe;
    }
  }
  float* gp = pre + ((long)b*12*V + p0z*VPL + (p0y+oyT)*130 + (p0x+oxT));
  float rmin[10], rsum[10];

  float* const b0 = A4;
  float* const b1 = A4 + A4SZ;

  // ---- load 4 rows (B,E,A,D) up front; C later (max 4-5 rows live) ----
  float rA[24],rB[24],rC[24],rD[24],rE[24];
  if (arow){
    load_row(gB,ax0,klass,zB,rB);
    load_row(gE,ax0,klass,zE,rE);
    load_row(gA,ax0,klass,false,rA);
    load_row(gD,ax0,klass,zD,rD);
    PIN24(rB); PIN24(rE); PIN24(rA); PIN24(rD);
  }

  // ---- 12 channels, double-buffered A4, 1 barrier/channel; yz lags aphase by 1 ----
  aphase<2,2>(rB,rE,b0,wb,bxg,arow);                    // c1
  __syncthreads();
  aphase<0,2>(rA,rE,b1,wb,bxg,arow);                    // c0
  yzphase(b0,fb,yzact,valid,gp,rmin,rsum,true , 1*V);
  __syncthreads();
  aphase<4,2>(rA,rE,b0,wb,bxg,arow);                    // c3
  yzphase(b1,fb,yzact,valid,gp,rmin,rsum,false, 0*V);
  __syncthreads();
  aphase<2,2>(rD,rE,b1,wb,bxg,arow);                    // c8 (last E use)
  if (arow){ load_row(gC,ax0,klass,zC,rC); PIN24(rC); }
  yzphase(b0,fb,yzact,valid,gp,rmin,rsum,false, 3*V);
  __syncthreads();
  aphase<2,0>(rB,rA,b0,wb,bxg,arow);                    // c2
  yzphase(b1,fb,yzact,valid,gp,rmin,rsum,false, 8*V);
  __syncthreads();
  aphase<4,2>(rA,rB,b1,wb,bxg,arow);                    // c4
  yzphase(b0,fb,yzact,valid,gp,rmin,rsum,false, 2*V);
  __syncthreads();
  aphase<2,2>(rC,rB,b0,wb,bxg,arow);                    // c6 (last B use)
  yzphase(b1,fb,yzact,valid,gp,rmin,rsum,false, 4*V);
  __syncthreads();
  aphase<2,0>(rC,rA,b1,wb,bxg,arow);                    // c5
  yzphase(b0,fb,yzact,valid,gp,rmin,rsum,false, 6*V);
  __syncthreads();
  aphase<2,4>(rC,rA,b0,wb,bxg,arow);                    // c7
  yzphase(b1,fb,yzact,valid,gp,rmin,rsum,false, 5*V);
  __syncthreads();
  aphase<2,2>(rD,rC,b1,wb,bxg,arow);                    // c11 (last C use)
  yzphase(b0,fb,yzact,valid,gp,rmin,rsum,false, 7*V);
  __syncthreads();
  aphase<2,0>(rD,rA,b0,wb,bxg,arow);                    // c9
  yzphase(b1,fb,yzact,valid,gp,rmin,rsum,false,11*V);
  __syncthreads();
  aphase<2,4>(rD,rA,b1,wb,bxg,arow);                    // c10
  yzphase(b0,fb,yzact,valid,gp,rmin,rsum,false, 9*V);
  __syncthreads();
  yzphase(b1,fb,yzact,valid,gp,rmin,rsum,false,10*V);

  // ---- deterministic partial sum of mind_var (raw scale) ----
  float vl = 0.f;
  if (valid){
    #pragma unroll
    for (int k=0;k<10;++k) vl += rsum[k]*(1.0f/12.0f) - rmin[k];
  }
  #pragma unroll
  for (int off=32; off>0; off>>=1) vl += __shfl_down(vl, off, 64);
  if ((tid&63)==0) wred[tid>>6] = vl;
  __syncthreads();
  if (tid==0) bsum[orig] = wred[0]+wred[1]+wred[2]+wred[3];
}

// ---------------- deterministic reduce for m ----------------
__global__ __launch_bounds__(256) void reduce_bsum(const float* __restrict__ bsum, float* wsf){
  __shared__ float sm[256];
  float s = 0.f;
  for (int i = threadIdx.x; i < NWG; i += 256) s += bsum[i];
  sm[threadIdx.x] = s;
  __syncthreads();
  for (int w = 128; w > 0; w >>= 1){
    if (threadIdx.x < w) sm[threadIdx.x] += sm[threadIdx.x + w];
    __syncthreads();
  }
  if (threadIdx.x == 0) wsf[2] = sm[0] * (1.0f/4394000.0f);
}

// ---------------- finalize: min/mean/clamp/exp in-place on raw ssd ----------------
__global__ __launch_bounds__(256) void final_kernel(float* __restrict__ out,
                                                    const float* __restrict__ wsf){
  const int q = blockIdx.x*256 + threadIdx.x;
  if (q >= 2*NV4) return;
  const float m = wsf[2];
  const float lo = m*0.001f, hi = m*1000.f;
  const int b = q / NV4;
  const int vq = q - b*NV4;
  float4* o4 = (float4*)out;
  const int ob = b*12*NV4 + vq;
  float4 p[12];
  #pragma unroll
  for (int c=0;c<12;++c) p[c] = o4[ob + c*NV4];
  float4 mn = p[0], sm = p[0];
  #pragma unroll
  for (int c=1;c<12;++c){
    mn.x = fminf(mn.x,p[c].x); mn.y = fminf(mn.y,p[c].y);
    mn.z = fminf(mn.z,p[c].z); mn.w = fminf(mn.w,p[c].w);
    sm.x += p[c].x; sm.y += p[c].y; sm.z += p[c].z; sm.w += p[c].w;
  }
  const float rx = 1.f/fminf(fmaxf(sm.x*(1.f/12.f)-mn.x, lo), hi);
  const float ry = 1.f/fminf(fmaxf(sm.y*(1.f/12.f)-mn.y, lo), hi);
  const float rz = 1.f/fminf(fmaxf(sm.z*(1.f/12.f)-mn.z, lo), hi);
  const float rw = 1.f/fminf(fmaxf(sm.w*(1.f/12.f)-mn.w, lo), hi);
  #pragma unroll
  for (int c=0;c<12;++c){
    float4 e;
    e.x = __expf(-(p[c].x-mn.x)*rx);
    e.y = __expf(-(p[c].y-mn.y)*ry);
    e.z = __expf(-(p[c].z-mn.z)*rz);
    e.w = __expf(-(p[c].w-mn.w)*rw);
    o4[ob + c*NV4] = e;
  }
}

extern "C" void kernel_launch(void* const* d_in, const int* in_sizes, int n_in,
                              void* d_out, int out_size, void* d_ws, size_t ws_size,
                              hipStream_t stream){
  (void)in_sizes; (void)n_in; (void)out_size; (void)ws_size;
  const float* x = (const float*)d_in[0];
  float* out = (float*)d_out;
  float* wsf = (float*)d_ws;
  float* bsum = (float*)((char*)d_ws + 64);

  hipLaunchKernelGGL(mind_main, dim3(NWG), dim3(256), 0, stream, x, out, bsum);
  hipLaunchKernelGGL(reduce_bsum, dim3(1), dim3(256), 0, stream, bsum, wsf);
  hipLaunchKernelGGL(final_kernel, dim3((2*NV4+255)/256), dim3(256), 0, stream, out, wsf);
}